// Round 1
// baseline (290.209 us; speedup 1.0000x reference)
//
#include <hip/hip_runtime.h>

#define MPTS  50000
#define NCH   128     // C
#define NH    32      // neighborhood
#define NCPG  16      // channels per group
#define NG    8       // groups
#define NK2   512     // H * CPG
#define NEG_SLOPE 0.1f
#define BN_EPS 1e-5f

// ---------------------------------------------------------------------------
// Kernel 1: t = s_feats @ w1 + b1  (50000x128, K=128), plus per-channel
// sum / sumsq partials via atomics (for training-mode BatchNorm).
// Block = 128 threads (one per output channel), 16 points per block.
// ---------------------------------------------------------------------------
__global__ __launch_bounds__(128)
void k1_gemm1(const float* __restrict__ sf, const float* __restrict__ w1,
              const float* __restrict__ b1, float* __restrict__ t,
              float* __restrict__ stats) {
    __shared__ float sfs[16][NCH];          // 8 KB input tile
    const int c  = threadIdx.x;             // 0..127
    const int m0 = blockIdx.x * 16;

    #pragma unroll
    for (int p = 0; p < 16; ++p)
        sfs[p][c] = sf[(size_t)(m0 + p) * NCH + c];
    __syncthreads();

    float acc[16];
    const float bias = b1[c];
    #pragma unroll
    for (int p = 0; p < 16; ++p) acc[p] = bias;

    for (int r = 0; r < NCH; ++r) {
        const float w = w1[r * NCH + c];    // coalesced across threads
        #pragma unroll
        for (int p = 0; p < 16; ++p)
            acc[p] += sfs[p][r] * w;        // LDS broadcast read
    }

    float s = 0.f, ss = 0.f;
    #pragma unroll
    for (int p = 0; p < 16; ++p) {
        t[(size_t)(m0 + p) * NCH + c] = acc[p];
        s  += acc[p];
        ss += acc[p] * acc[p];
    }
    atomicAdd(&stats[c],        s);
    atomicAdd(&stats[NCH + c],  ss);
}

// ---------------------------------------------------------------------------
// Kernel 2: finalize BN coefficients:  h = t*a + b  with
//   a = gamma * rsqrt(var + eps),  b = beta - mu * a
// ---------------------------------------------------------------------------
__global__ __launch_bounds__(NCH)
void k2_stats(const float* __restrict__ stats, const float* __restrict__ gamma,
              const float* __restrict__ beta, float* __restrict__ coef) {
    const int c = threadIdx.x;
    const float inv_m = 1.0f / (float)MPTS;
    const float mu  = stats[c] * inv_m;
    const float var = stats[NCH + c] * inv_m - mu * mu;
    const float a   = gamma[c] * rsqrtf(var + BN_EPS);
    coef[c]       = a;
    coef[NCH + c] = beta[c] - mu * a;
}

// ---------------------------------------------------------------------------
// Kernel 3 (fused): per 16-point tile
//   h    = leaky(t*a + b)                      (16x128, LDS)
//   attn = h @ w2 + b2                         (16x512, LDS)
//   out[m,c] = sum_h sf[idx[m,h], c] * attn[m, h*16 + (c>>3)]
// Block = 256 threads.
// ---------------------------------------------------------------------------
__global__ __launch_bounds__(256)
void k3_fused(const float* __restrict__ t, const float* __restrict__ coef,
              const float* __restrict__ w2, const float* __restrict__ b2,
              const float* __restrict__ sf, const int* __restrict__ nidx,
              float* __restrict__ out) {
    __shared__ float hsh[16][NCH];    //  8 KB
    __shared__ float attn[16][NK2];   // 32 KB
    __shared__ int   idxs[16][NH];    //  2 KB

    const int tid = threadIdx.x;      // 0..255
    const int m0  = blockIdx.x * 16;

    // ---- stage 0: load h = leaky(bn(t)) tile, and neighbor indices ----
    {
        const int c  = tid & 127;
        const int ph = tid >> 7;      // 0..1
        const float a = coef[c];
        const float b = coef[NCH + c];
        #pragma unroll
        for (int p = ph; p < 16; p += 2) {
            float v = t[(size_t)(m0 + p) * NCH + c] * a + b;
            hsh[p][c] = (v >= 0.f) ? v : NEG_SLOPE * v;
        }
        #pragma unroll
        for (int i = tid; i < 16 * NH; i += 256)
            idxs[i >> 5][i & 31] = nidx[(size_t)(m0 + (i >> 5)) * NH + (i & 31)];
    }
    __syncthreads();

    // ---- stage 1: attn tile GEMM. thread owns columns k=tid, tid+256 ----
    {
        float acc0[16], acc1[16];
        const float bb0 = b2[tid];
        const float bb1 = b2[tid + 256];
        #pragma unroll
        for (int p = 0; p < 16; ++p) { acc0[p] = bb0; acc1[p] = bb1; }

        for (int r = 0; r < NCH; ++r) {
            const float w0 = w2[r * NK2 + tid];        // coalesced
            const float wA = w2[r * NK2 + tid + 256];  // coalesced
            #pragma unroll
            for (int p = 0; p < 16; ++p) {
                const float hv = hsh[p][r];            // LDS broadcast
                acc0[p] += hv * w0;
                acc1[p] += hv * wA;
            }
        }
        #pragma unroll
        for (int p = 0; p < 16; ++p) {
            attn[p][tid]       = acc0[p];
            attn[p][tid + 256] = acc1[p];
        }
    }
    __syncthreads();

    // ---- stage 2: neighbor gather + weighted reduction over H ----
    {
        const int c  = tid & 127;
        const int ph = tid >> 7;
        #pragma unroll
        for (int p = ph; p < 16; p += 2) {
            const int m = m0 + p;
            float acc = 0.f;
            #pragma unroll
            for (int h = 0; h < NH; ++h) {
                const int n   = idxs[p][h];
                const float f = sf[(size_t)n * NCH + c];     // coalesced row read
                acc += f * attn[p][h * NCPG + (c >> 3)];     // LDS, 8-lane broadcast
            }
            out[(size_t)m * NCH + c] = acc;
        }
    }
}

// ---------------------------------------------------------------------------
extern "C" void kernel_launch(void* const* d_in, const int* in_sizes, int n_in,
                              void* d_out, int out_size, void* d_ws, size_t ws_size,
                              hipStream_t stream) {
    // setup_inputs order:
    // 0 q_pts (unused) | 1 s_pts (unused) | 2 s_feats | 3 neighb_inds
    // 4 w1 | 5 b1 | 6 gamma1 | 7 beta1 | 8 w2 | 9 b2
    const float* sf    = (const float*)d_in[2];
    const int*   nidx  = (const int*)  d_in[3];
    const float* w1    = (const float*)d_in[4];
    const float* b1    = (const float*)d_in[5];
    const float* gamma = (const float*)d_in[6];
    const float* beta  = (const float*)d_in[7];
    const float* w2    = (const float*)d_in[8];
    const float* b2    = (const float*)d_in[9];
    float* out = (float*)d_out;

    char*  ws    = (char*)d_ws;
    float* t     = (float*)ws;                                  // 25.6 MB
    float* stats = (float*)(ws + (size_t)MPTS * NCH * sizeof(float)); // 256 f32
    float* coef  = stats + 2 * NCH;                             // 256 f32

    // stats must start at zero every call (ws is not re-poisoned between replays)
    hipMemsetAsync(stats, 0, 2 * NCH * sizeof(float), stream);

    k1_gemm1<<<MPTS / 16, 128, 0, stream>>>(sf, w1, b1, t, stats);
    k2_stats<<<1, NCH, 0, stream>>>(stats, gamma, beta, coef);
    k3_fused<<<MPTS / 16, 256, 0, stream>>>(t, coef, w2, b2, sf, nidx, out);
}